// Round 2
// baseline (1014.660 us; speedup 1.0000x reference)
//
#include <hip/hip_runtime.h>
#include <stdint.h>

#define T_TOK 8192
#define H_DIM 1024
#define I_DIM 2752
#define E_NUM 8

typedef unsigned short ushort_t;
typedef short bf16x8 __attribute__((ext_vector_type(8)));
typedef float f32x4 __attribute__((ext_vector_type(4)));

__device__ __forceinline__ unsigned short f2bf(float f){
  union { float f; uint32_t u; } v; v.f = f;
  return (unsigned short)((v.u + 0x7fffu + ((v.u >> 16) & 1u)) >> 16);
}

// ---------------- convert fp32 -> bf16 ----------------
__global__ void cvt_kernel(const float4* __restrict__ src, ushort4* __restrict__ dst, int n4){
  int stride = gridDim.x * blockDim.x;
  for (int i = blockIdx.x * blockDim.x + threadIdx.x; i < n4; i += stride){
    float4 v = src[i];
    ushort4 o;
    o.x = f2bf(v.x); o.y = f2bf(v.y); o.z = f2bf(v.z); o.w = f2bf(v.w);
    dst[i] = o;
  }
}

__global__ void fill_kernel(float* __restrict__ p, float v, int n){
  int i = blockIdx.x * blockDim.x + threadIdx.x;
  if (i < n) p[i] = v;
}

// ---------------- gate: fp32 logits, softmax-top2 ----------------
__global__ void gate_kernel(const float* __restrict__ x, const float* __restrict__ gw,
                            int* __restrict__ topk_idx, float* __restrict__ topk_w,
                            int* __restrict__ counts){
  int lane = threadIdx.x & 63;
  int wv = threadIdx.x >> 6;
  int t = blockIdx.x * 4 + wv;
  const float* xt = x + (size_t)t * H_DIM;
  float acc[E_NUM];
  #pragma unroll
  for (int e = 0; e < E_NUM; e++) acc[e] = 0.f;
  for (int c = 0; c < H_DIM / 64; c++){
    float xv = xt[c * 64 + lane];
    #pragma unroll
    for (int e = 0; e < E_NUM; e++) acc[e] += xv * gw[e * H_DIM + c * 64 + lane];
  }
  #pragma unroll
  for (int e = 0; e < E_NUM; e++){
    #pragma unroll
    for (int o = 32; o; o >>= 1) acc[e] += __shfl_xor(acc[e], o);
  }
  if (lane == 0){
    int i1 = 0; float l1 = acc[0];
    #pragma unroll
    for (int e = 1; e < E_NUM; e++) if (acc[e] > l1){ l1 = acc[e]; i1 = e; }
    int i2 = -1; float l2 = -1e30f;
    #pragma unroll
    for (int e = 0; e < E_NUM; e++) if (e != i1 && acc[e] > l2){ l2 = acc[e]; i2 = e; }
    // softmax over 8 then renorm over top-2 == exp-renorm over top-2 logits
    float e2 = expf(l2 - l1);
    float denom = 1.0f + e2;
    topk_idx[t * 2 + 0] = i1; topk_idx[t * 2 + 1] = i2;
    topk_w[t * 2 + 0] = 1.0f / denom; topk_w[t * 2 + 1] = e2 / denom;
    atomicAdd(&counts[i1], 1); atomicAdd(&counts[i2], 1);
  }
}

__global__ void offsets_kernel(const int* __restrict__ counts, int* __restrict__ offs,
                               int* __restrict__ cursor){
  if (threadIdx.x == 0 && blockIdx.x == 0){
    int a = 0;
    for (int e = 0; e < E_NUM; e++){ offs[e] = a; cursor[e] = a; a += counts[e]; }
    offs[E_NUM] = a;
  }
}

__global__ void scatter_kernel(const int* __restrict__ topk_idx, const float* __restrict__ topk_w,
                               int* __restrict__ cursor, int* __restrict__ perm,
                               float* __restrict__ pw){
  int t = blockIdx.x * blockDim.x + threadIdx.x;
  if (t >= T_TOK) return;
  #pragma unroll
  for (int k = 0; k < 2; k++){
    int e = topk_idx[t * 2 + k];
    int pos = atomicAdd(&cursor[e], 1);
    perm[pos] = t;
    pw[pos] = topk_w[t * 2 + k];
  }
}

// ---------------- GEMM1: h = silu(X@Wg^T) * (X@Wu^T) * route_w ----------------
// C[M,N] with A=[M,K=1024] gathered token rows (bf16), Wg/Wu=[N=I,K] (bf16, [out,in])
// 128x128 tile, 4 waves 2x2, 16x16x32 MFMA, reg-staged LDS, BK=32.
__global__ __launch_bounds__(256, 2) void gemm1_kernel(
    const ushort_t* __restrict__ Xb,
    const ushort_t* __restrict__ Wg,
    const ushort_t* __restrict__ Wu,
    ushort_t* __restrict__ Hb,
    const int* __restrict__ offs,   // null => single "expert" (shared) of fixedM rows
    const int* __restrict__ perm,   // null => identity
    const float* __restrict__ pw,   // null => weight 1
    int fixedM)
{
  __shared__ __align__(16) ushort_t ldsA[128 * 32];
  __shared__ __align__(16) ushort_t ldsG[128 * 32];
  __shared__ __align__(16) ushort_t ldsU[128 * 32];

  const int tid = threadIdx.x;
  const int lane = tid & 63;
  const int wv = tid >> 6;
  const int wr = wv >> 1;
  const int wc = wv & 1;

  int e = 0, row0 = 0, mEnd = fixedM, maxRow = fixedM - 1;
  if (offs){
    int bx = blockIdx.x, base = 0;
    bool found = false;
    for (e = 0; e < E_NUM; ++e){
      int m0 = offs[e], m1 = offs[e + 1];
      int nt = (m1 - m0 + 127) >> 7;
      if (bx < base + nt){ row0 = m0 + (bx - base) * 128; mEnd = m1; found = true; break; }
      base += nt;
    }
    if (!found) return;
    maxRow = offs[E_NUM] - 1;
  } else {
    row0 = blockIdx.x * 128;
  }

  const ushort_t* Weg = Wg + (size_t)e * I_DIM * H_DIM;
  const ushort_t* Weu = Wu + (size_t)e * I_DIM * H_DIM;

  const int r0 = tid >> 2;          // 0..63 : row within half-tile
  const int kc = (tid & 3) << 3;    // 0,8,16,24 : K-element offset

  int gr0 = row0 + r0;        if (gr0 > maxRow) gr0 = maxRow;
  int gr1 = row0 + 64 + r0;   if (gr1 > maxRow) gr1 = maxRow;
  const int tok0 = perm ? perm[gr0] : gr0;
  const int tok1 = perm ? perm[gr1] : gr1;
  const ushort_t* srcA0 = Xb + (size_t)tok0 * H_DIM + kc;
  const ushort_t* srcA1 = Xb + (size_t)tok1 * H_DIM + kc;

  const int nb = blockIdx.y * 128;
  int n0 = nb + r0;       if (n0 > I_DIM - 1) n0 = I_DIM - 1;
  int n1 = nb + 64 + r0;  if (n1 > I_DIM - 1) n1 = I_DIM - 1;
  const ushort_t* srcG0 = Weg + (size_t)n0 * H_DIM + kc;
  const ushort_t* srcG1 = Weg + (size_t)n1 * H_DIM + kc;
  const ushort_t* srcU0 = Weu + (size_t)n0 * H_DIM + kc;
  const ushort_t* srcU1 = Weu + (size_t)n1 * H_DIM + kc;

  f32x4 accg[4][4], accu[4][4];
  const f32x4 zero = {0.f, 0.f, 0.f, 0.f};
  #pragma unroll
  for (int m = 0; m < 4; m++)
    #pragma unroll
    for (int n = 0; n < 4; n++){ accg[m][n] = zero; accu[m][n] = zero; }

  // prefetch K-step 0
  bf16x8 pa0 = *(const bf16x8*)srcA0;
  bf16x8 pa1 = *(const bf16x8*)srcA1;
  bf16x8 pg0 = *(const bf16x8*)srcG0;
  bf16x8 pg1 = *(const bf16x8*)srcG1;
  bf16x8 pu0 = *(const bf16x8*)srcU0;
  bf16x8 pu1 = *(const bf16x8*)srcU1;

  const ushort_t* pAr = ldsA + ((wr * 64 + (lane & 15)) * 32 + ((lane >> 4) << 3));
  const ushort_t* pGr = ldsG + ((wc * 64 + (lane & 15)) * 32 + ((lane >> 4) << 3));
  const ushort_t* pUr = ldsU + ((wc * 64 + (lane & 15)) * 32 + ((lane >> 4) << 3));

  for (int k0 = 0; k0 < H_DIM; k0 += 32){
    __syncthreads();                      // previous compute done: LDS free
    *(bf16x8*)(ldsA + tid * 8)        = pa0;
    *(bf16x8*)(ldsA + 2048 + tid * 8) = pa1;
    *(bf16x8*)(ldsG + tid * 8)        = pg0;
    *(bf16x8*)(ldsG + 2048 + tid * 8) = pg1;
    *(bf16x8*)(ldsU + tid * 8)        = pu0;
    *(bf16x8*)(ldsU + 2048 + tid * 8) = pu1;
    __syncthreads();                      // LDS tile ready
    if (k0 + 32 < H_DIM){                 // prefetch next K-step (overlaps MFMA)
      pa0 = *(const bf16x8*)(srcA0 + k0 + 32);
      pa1 = *(const bf16x8*)(srcA1 + k0 + 32);
      pg0 = *(const bf16x8*)(srcG0 + k0 + 32);
      pg1 = *(const bf16x8*)(srcG1 + k0 + 32);
      pu0 = *(const bf16x8*)(srcU0 + k0 + 32);
      pu1 = *(const bf16x8*)(srcU1 + k0 + 32);
    }
    bf16x8 a[4], bg[4], bu[4];
    #pragma unroll
    for (int m = 0; m < 4; m++) a[m]  = *(const bf16x8*)(pAr + m * 16 * 32);
    #pragma unroll
    for (int n = 0; n < 4; n++) bg[n] = *(const bf16x8*)(pGr + n * 16 * 32);
    #pragma unroll
    for (int n = 0; n < 4; n++) bu[n] = *(const bf16x8*)(pUr + n * 16 * 32);
    #pragma unroll
    for (int m = 0; m < 4; m++)
      #pragma unroll
      for (int n = 0; n < 4; n++){
        accg[m][n] = __builtin_amdgcn_mfma_f32_16x16x32_bf16(a[m], bg[n], accg[m][n], 0, 0, 0);
        accu[m][n] = __builtin_amdgcn_mfma_f32_16x16x32_bf16(a[m], bu[n], accu[m][n], 0, 0, 0);
      }
  }

  // epilogue: silu(g)*u*wt -> bf16 h
  #pragma unroll
  for (int m = 0; m < 4; m++){
    #pragma unroll
    for (int j = 0; j < 4; j++){
      int gr = row0 + wr * 64 + m * 16 + ((lane >> 4) << 2) + j;
      if (gr < mEnd){
        float wt = pw ? pw[gr] : 1.0f;
        ushort_t* hrow = Hb + (size_t)gr * I_DIM;
        #pragma unroll
        for (int n = 0; n < 4; n++){
          int c = nb + wc * 64 + n * 16 + (lane & 15);
          if (c < I_DIM){
            float gv = accg[m][n][j];
            float uv = accu[m][n][j];
            float hv = (gv / (1.0f + __expf(-gv))) * uv * wt;
            hrow[c] = f2bf(hv);
          }
        }
      }
    }
  }
}

// ---------------- GEMM2: y[tok] (+)= h @ Wd^T ----------------
__global__ __launch_bounds__(256, 2) void gemm2_kernel(
    const ushort_t* __restrict__ Hb,
    const ushort_t* __restrict__ Wd,   // [H_DIM, I_DIM] per expert (bf16)
    float* __restrict__ Y,
    const int* __restrict__ offs,
    const int* __restrict__ perm,
    int fixedM, int doAtomic)
{
  __shared__ __align__(16) ushort_t ldsA[128 * 32];
  __shared__ __align__(16) ushort_t ldsB[128 * 32];

  const int tid = threadIdx.x;
  const int lane = tid & 63;
  const int wv = tid >> 6;
  const int wr = wv >> 1;
  const int wc = wv & 1;

  int e = 0, row0 = 0, mEnd = fixedM, maxRow = fixedM - 1;
  if (offs){
    int bx = blockIdx.x, base = 0;
    bool found = false;
    for (e = 0; e < E_NUM; ++e){
      int m0 = offs[e], m1 = offs[e + 1];
      int nt = (m1 - m0 + 127) >> 7;
      if (bx < base + nt){ row0 = m0 + (bx - base) * 128; mEnd = m1; found = true; break; }
      base += nt;
    }
    if (!found) return;
    maxRow = offs[E_NUM] - 1;
  } else {
    row0 = blockIdx.x * 128;
  }

  const ushort_t* Wde = Wd + (size_t)e * H_DIM * I_DIM;

  const int r0 = tid >> 2;
  const int kc = (tid & 3) << 3;

  int gr0 = row0 + r0;        if (gr0 > maxRow) gr0 = maxRow;
  int gr1 = row0 + 64 + r0;   if (gr1 > maxRow) gr1 = maxRow;
  const ushort_t* srcA0 = Hb + (size_t)gr0 * I_DIM + kc;
  const ushort_t* srcA1 = Hb + (size_t)gr1 * I_DIM + kc;

  const int nb = blockIdx.y * 128;          // N = H_DIM = 1024, exact tiles
  const int n0 = nb + r0;
  const int n1 = nb + 64 + r0;
  const ushort_t* srcB0 = Wde + (size_t)n0 * I_DIM + kc;
  const ushort_t* srcB1 = Wde + (size_t)n1 * I_DIM + kc;

  f32x4 acc[4][4];
  const f32x4 zero = {0.f, 0.f, 0.f, 0.f};
  #pragma unroll
  for (int m = 0; m < 4; m++)
    #pragma unroll
    for (int n = 0; n < 4; n++) acc[m][n] = zero;

  bf16x8 pa0 = *(const bf16x8*)srcA0;
  bf16x8 pa1 = *(const bf16x8*)srcA1;
  bf16x8 pb0 = *(const bf16x8*)srcB0;
  bf16x8 pb1 = *(const bf16x8*)srcB1;

  const ushort_t* pAr = ldsA + ((wr * 64 + (lane & 15)) * 32 + ((lane >> 4) << 3));
  const ushort_t* pBr = ldsB + ((wc * 64 + (lane & 15)) * 32 + ((lane >> 4) << 3));

  for (int k0 = 0; k0 < I_DIM; k0 += 32){
    __syncthreads();
    *(bf16x8*)(ldsA + tid * 8)        = pa0;
    *(bf16x8*)(ldsA + 2048 + tid * 8) = pa1;
    *(bf16x8*)(ldsB + tid * 8)        = pb0;
    *(bf16x8*)(ldsB + 2048 + tid * 8) = pb1;
    __syncthreads();
    if (k0 + 32 < I_DIM){
      pa0 = *(const bf16x8*)(srcA0 + k0 + 32);
      pa1 = *(const bf16x8*)(srcA1 + k0 + 32);
      pb0 = *(const bf16x8*)(srcB0 + k0 + 32);
      pb1 = *(const bf16x8*)(srcB1 + k0 + 32);
    }
    bf16x8 a[4], b[4];
    #pragma unroll
    for (int m = 0; m < 4; m++) a[m] = *(const bf16x8*)(pAr + m * 16 * 32);
    #pragma unroll
    for (int n = 0; n < 4; n++) b[n] = *(const bf16x8*)(pBr + n * 16 * 32);
    #pragma unroll
    for (int m = 0; m < 4; m++)
      #pragma unroll
      for (int n = 0; n < 4; n++)
        acc[m][n] = __builtin_amdgcn_mfma_f32_16x16x32_bf16(a[m], b[n], acc[m][n], 0, 0, 0);
  }

  #pragma unroll
  for (int m = 0; m < 4; m++){
    #pragma unroll
    for (int j = 0; j < 4; j++){
      int gr = row0 + wr * 64 + m * 16 + ((lane >> 4) << 2) + j;
      if (gr < mEnd){
        int tok = perm ? perm[gr] : gr;
        float* yrow = Y + (size_t)tok * H_DIM;
        #pragma unroll
        for (int n = 0; n < 4; n++){
          int c = nb + wc * 64 + n * 16 + (lane & 15);
          float v = acc[m][n][j];
          if (doAtomic) atomicAdd(&yrow[c], v);
          else          yrow[c] = v;
        }
      }
    }
  }
}

// ---------------- launch ----------------
extern "C" void kernel_launch(void* const* d_in, const int* in_sizes, int n_in,
                              void* d_out, int out_size, void* d_ws, size_t ws_size,
                              hipStream_t stream) {
  const float* x      = (const float*)d_in[0];
  const float* gate_w = (const float*)d_in[1];
  const float* wg     = (const float*)d_in[2];
  const float* wu     = (const float*)d_in[3];
  const float* wd     = (const float*)d_in[4];
  const float* swg    = (const float*)d_in[5];
  const float* swu    = (const float*)d_in[6];
  const float* swd    = (const float*)d_in[7];
  float* Y = (float*)d_out;
  char* ws = (char*)d_ws;

  constexpr size_t XB_SZ   = (size_t)T_TOK * H_DIM * 2;            // 16,777,216
  constexpr size_t WEXP_SZ = (size_t)E_NUM * I_DIM * H_DIM * 2;    // 45,088,768
  constexpr size_t SW_SZ   = (size_t)I_DIM * H_DIM * 2;            //  5,636,096
  constexpr size_t H_SZ    = (size_t)T_TOK * 2 * I_DIM * 2;        // 90,177,536

  constexpr size_t XB_OFF  = 0;
  constexpr size_t WG_OFF  = XB_OFF + XB_SZ;
  constexpr size_t WU_OFF  = WG_OFF + WEXP_SZ;
  constexpr size_t WD_OFF  = WU_OFF + WEXP_SZ;
  constexpr size_t SWG_OFF = WD_OFF + WEXP_SZ;
  constexpr size_t SWU_OFF = SWG_OFF + SW_SZ;
  constexpr size_t SWD_OFF = SWU_OFF + SW_SZ;
  constexpr size_t H_OFF   = SWD_OFF + SW_SZ;
  constexpr size_t META_OFF = H_OFF + H_SZ;
  constexpr size_t TI_OFF  = META_OFF;            // topk_idx: 16384 int
  constexpr size_t TW_OFF  = TI_OFF + 65536;      // topk_w
  constexpr size_t PM_OFF  = TW_OFF + 65536;      // perm
  constexpr size_t PW_OFF  = PM_OFF + 65536;      // pw
  constexpr size_t CNT_OFF = PW_OFF + 65536;      // counts(8) offs(9) cursor(8)
  constexpr size_t NEEDED  = CNT_OFF + 4096;

  if (ws_size < NEEDED){
    // sentinel: clearly-wrong constant output signals "workspace too small"
    fill_kernel<<<(out_size + 255) / 256, 256, 0, stream>>>(Y, 12345.0f, out_size);
    return;
  }

  ushort_t* xb   = (ushort_t*)(ws + XB_OFF);
  ushort_t* wgb  = (ushort_t*)(ws + WG_OFF);
  ushort_t* wub  = (ushort_t*)(ws + WU_OFF);
  ushort_t* wdb  = (ushort_t*)(ws + WD_OFF);
  ushort_t* swgb = (ushort_t*)(ws + SWG_OFF);
  ushort_t* swub = (ushort_t*)(ws + SWU_OFF);
  ushort_t* swdb = (ushort_t*)(ws + SWD_OFF);
  ushort_t* hb   = (ushort_t*)(ws + H_OFF);
  int*   topk_idx = (int*)(ws + TI_OFF);
  float* topk_w   = (float*)(ws + TW_OFF);
  int*   perm     = (int*)(ws + PM_OFF);
  float* pw       = (float*)(ws + PW_OFF);
  int*   counts   = (int*)(ws + CNT_OFF);
  int*   offs     = counts + 8;
  int*   cursor   = offs + 9;

  // fp32 -> bf16 conversions
  cvt_kernel<<<2048, 256, 0, stream>>>((const float4*)x,   (ushort4*)xb,   (int)(T_TOK * H_DIM / 4));
  cvt_kernel<<<2048, 256, 0, stream>>>((const float4*)wg,  (ushort4*)wgb,  (int)(E_NUM * (size_t)I_DIM * H_DIM / 4));
  cvt_kernel<<<2048, 256, 0, stream>>>((const float4*)wu,  (ushort4*)wub,  (int)(E_NUM * (size_t)I_DIM * H_DIM / 4));
  cvt_kernel<<<2048, 256, 0, stream>>>((const float4*)wd,  (ushort4*)wdb,  (int)(E_NUM * (size_t)I_DIM * H_DIM / 4));
  cvt_kernel<<<1024, 256, 0, stream>>>((const float4*)swg, (ushort4*)swgb, (int)((size_t)I_DIM * H_DIM / 4));
  cvt_kernel<<<1024, 256, 0, stream>>>((const float4*)swu, (ushort4*)swub, (int)((size_t)I_DIM * H_DIM / 4));
  cvt_kernel<<<1024, 256, 0, stream>>>((const float4*)swd, (ushort4*)swdb, (int)((size_t)I_DIM * H_DIM / 4));

  hipMemsetAsync(counts, 0, 8 * sizeof(int), stream);
  gate_kernel<<<T_TOK / 4, 256, 0, stream>>>(x, gate_w, topk_idx, topk_w, counts);
  offsets_kernel<<<1, 64, 0, stream>>>(counts, offs, cursor);
  scatter_kernel<<<T_TOK / 256, 256, 0, stream>>>(topk_idx, topk_w, cursor, perm, pw);

  // shared expert (writes y with '=', covering all of d_out)
  gemm1_kernel<<<dim3(T_TOK / 128, (I_DIM + 127) / 128), 256, 0, stream>>>(
      xb, swgb, swub, hb, nullptr, nullptr, nullptr, T_TOK);
  gemm2_kernel<<<dim3(T_TOK / 128, H_DIM / 128), 256, 0, stream>>>(
      hb, swdb, Y, nullptr, nullptr, T_TOK, 0);

  // routed experts (grouped GEMM over perm-ordered rows; atomicAdd combine)
  constexpr int MAX_TILES = (T_TOK * 2) / 128 + E_NUM;   // 136
  gemm1_kernel<<<dim3(MAX_TILES, (I_DIM + 127) / 128), 256, 0, stream>>>(
      xb, wgb, wub, hb, offs, perm, pw, 0);
  gemm2_kernel<<<dim3(MAX_TILES, H_DIM / 128), 256, 0, stream>>>(
      hb, wdb, Y, offs, perm, 0, 1);
}